// Round 1
// baseline (378.187 us; speedup 1.0000x reference)
//
#include <hip/hip_runtime.h>
#include <hip/hip_bf16.h>

// ---------------------------------------------------------------------------
// DiffPool (edge_index unused by reference):
//   s      = softmax(x @ Wp + bp)          [N,64]
//   M      = s^T x                          [64,512]   (+ colsum(s))
//   pooled = M @ We + colsum(s) (outer) be  [64,512]
//   out    = pooled @ Wo + bo               [1,64,256]
// Key trick: s^T (x We + be) == (s^T x) We + colsum(s) be^T  -> no N x F GEMM.
// ---------------------------------------------------------------------------

#define FDIM 512
#define CDIM 64
#define ODIM 256
#define NCHUNKS 64   // kernel B n-chunks

// ------------------------- Kernel A: s = softmax(x Wp + bp) ----------------
// 64 rows / block, 256 threads. thread t: c = t&63 (cluster), g = t>>6 (row
// group of 16 rows). One wave == one g => row softmax is a wave reduction.
__global__ __launch_bounds__(256) void kA(const float* __restrict__ x,
                                          const float* __restrict__ Wp,
                                          const float* __restrict__ bp,
                                          float* __restrict__ s_out,
                                          float* __restrict__ colsum,
                                          int N) {
    __shared__ float xs[64][64];    // 16 KB  x tile  [row][k]
    __shared__ float wps[64][64];   // 16 KB  Wp tile [k][c]
    __shared__ float csums[4][64];

    const int t = threadIdx.x;
    const int c = t & 63;
    const int g = t >> 6;
    const int row0 = blockIdx.x * 64;

    float acc[16];
#pragma unroll
    for (int i = 0; i < 16; ++i) acc[i] = 0.f;

    for (int kt = 0; kt < FDIM; kt += 64) {
        // cooperative tile loads (float4, coalesced)
#pragma unroll
        for (int i = 0; i < 4; ++i) {
            int v  = t + i * 256;          // 0..1023
            int r  = v >> 4;               // 0..63
            int kk = (v & 15) << 2;        // 0..60
            float4 val = make_float4(0.f, 0.f, 0.f, 0.f);
            if (row0 + r < N)
                val = *(const float4*)(x + (size_t)(row0 + r) * FDIM + kt + kk);
            *(float4*)&xs[r][kk] = val;
            *(float4*)&wps[r][kk] =
                *(const float4*)(Wp + (size_t)(kt + r) * CDIM + kk);
        }
        __syncthreads();

        for (int k = 0; k < 64; k += 4) {
            float w0 = wps[k + 0][c];
            float w1 = wps[k + 1][c];
            float w2 = wps[k + 2][c];
            float w3 = wps[k + 3][c];
#pragma unroll
            for (int r = 0; r < 16; ++r) {
                float4 xv = *(const float4*)&xs[g * 16 + r][k];
                acc[r] = fmaf(xv.x, w0, acc[r]);
                acc[r] = fmaf(xv.y, w1, acc[r]);
                acc[r] = fmaf(xv.z, w2, acc[r]);
                acc[r] = fmaf(xv.w, w3, acc[r]);
            }
        }
        __syncthreads();
    }

    const float bpc = bp[c];
    float csum_local = 0.f;
#pragma unroll 1
    for (int r = 0; r < 16; ++r) {
        float v = acc[r] + bpc;
        float m = v;
#pragma unroll
        for (int off = 32; off > 0; off >>= 1)
            m = fmaxf(m, __shfl_xor(m, off));
        float e = __expf(v - m);
        float sum = e;
#pragma unroll
        for (int off = 32; off > 0; off >>= 1)
            sum += __shfl_xor(sum, off);
        float sv = e / sum;
        int row = row0 + g * 16 + r;
        if (row < N) {
            s_out[(size_t)row * CDIM + c] = sv;
            csum_local += sv;
        }
    }

    csums[g][c] = csum_local;
    __syncthreads();
    if (g == 0) {
        float tot = csums[0][c] + csums[1][c] + csums[2][c] + csums[3][c];
        atomicAdd(&colsum[c], tot);
    }
}

// ------------------------- Kernel B: M = s^T x -----------------------------
// grid (NCHUNKS, 8 f-tiles), 256 threads. thread t: f = f0 + (t&63),
// clusters c0..c0+15 with c0 = (t>>6)*16. s staged in LDS (broadcast reads).
__global__ __launch_bounds__(256) void kB(const float* __restrict__ x,
                                          const float* __restrict__ s,
                                          float* __restrict__ M,
                                          int N, int rch) {
    __shared__ float sl[64][64];   // 16 KB s tile [row][c]

    const int t  = threadIdx.x;
    const int g  = t >> 6;
    const int c0 = g * 16;
    const int f  = blockIdx.y * 64 + (t & 63);
    const int r0 = blockIdx.x * rch;
    const int rend = min(r0 + rch, N);

    float acc[16];
#pragma unroll
    for (int i = 0; i < 16; ++i) acc[i] = 0.f;

    for (int rc = r0; rc < rend; rc += 64) {
        __syncthreads();
#pragma unroll
        for (int i = 0; i < 4; ++i) {
            int v  = t + i * 256;
            int r  = v >> 4;
            int cc = (v & 15) << 2;
            float4 val = make_float4(0.f, 0.f, 0.f, 0.f);
            if (rc + r < rend)
                val = *(const float4*)(s + (size_t)(rc + r) * CDIM + cc);
            *(float4*)&sl[r][cc] = val;
        }
        __syncthreads();

        const int nr = min(64, rend - rc);
#pragma unroll 4
        for (int rr = 0; rr < nr; ++rr) {
            float xv = x[(size_t)(rc + rr) * FDIM + f];
            float4 s0 = *(const float4*)&sl[rr][c0 + 0];
            float4 s1 = *(const float4*)&sl[rr][c0 + 4];
            float4 s2 = *(const float4*)&sl[rr][c0 + 8];
            float4 s3 = *(const float4*)&sl[rr][c0 + 12];
            acc[0]  = fmaf(s0.x, xv, acc[0]);
            acc[1]  = fmaf(s0.y, xv, acc[1]);
            acc[2]  = fmaf(s0.z, xv, acc[2]);
            acc[3]  = fmaf(s0.w, xv, acc[3]);
            acc[4]  = fmaf(s1.x, xv, acc[4]);
            acc[5]  = fmaf(s1.y, xv, acc[5]);
            acc[6]  = fmaf(s1.z, xv, acc[6]);
            acc[7]  = fmaf(s1.w, xv, acc[7]);
            acc[8]  = fmaf(s2.x, xv, acc[8]);
            acc[9]  = fmaf(s2.y, xv, acc[9]);
            acc[10] = fmaf(s2.z, xv, acc[10]);
            acc[11] = fmaf(s2.w, xv, acc[11]);
            acc[12] = fmaf(s3.x, xv, acc[12]);
            acc[13] = fmaf(s3.y, xv, acc[13]);
            acc[14] = fmaf(s3.z, xv, acc[14]);
            acc[15] = fmaf(s3.w, xv, acc[15]);
        }
    }

#pragma unroll
    for (int j = 0; j < 16; ++j)
        atomicAdd(&M[(size_t)(c0 + j) * FDIM + f], acc[j]);
}

// ---------------- Kernel C1: pooled = M We + colsum (outer) be -------------
// grid (64 clusters, 4 k-splits), 256 threads; outputs f = t and t+256.
__global__ __launch_bounds__(256) void kC1(const float* __restrict__ M,
                                           const float* __restrict__ colsum,
                                           const float* __restrict__ We,
                                           const float* __restrict__ be,
                                           float* __restrict__ pooled) {
    __shared__ float mrow[128];
    const int c  = blockIdx.x;
    const int ks = blockIdx.y;           // k range [ks*128, ks*128+128)
    const int t  = threadIdx.x;

    if (t < 128) mrow[t] = M[(size_t)c * FDIM + ks * 128 + t];
    __syncthreads();

    float a0 = 0.f, a1 = 0.f;
    if (ks == 0) {
        float cs = colsum[c];
        a0 = cs * be[t];
        a1 = cs * be[t + 256];
    }
#pragma unroll 4
    for (int k = 0; k < 128; ++k) {
        float m = mrow[k];
        const float* wrow = We + (size_t)(ks * 128 + k) * FDIM;
        a0 = fmaf(m, wrow[t], a0);
        a1 = fmaf(m, wrow[t + 256], a1);
    }
    atomicAdd(&pooled[(size_t)c * FDIM + t], a0);
    atomicAdd(&pooled[(size_t)c * FDIM + t + 256], a1);
}

// ---------------- Kernel C2: out = pooled Wo + bo --------------------------
// grid (64 clusters, 4 k-splits), 256 threads; output o = t.
__global__ __launch_bounds__(256) void kC2(const float* __restrict__ pooled,
                                           const float* __restrict__ Wo,
                                           const float* __restrict__ bo,
                                           float* __restrict__ out) {
    __shared__ float prow[128];
    const int c  = blockIdx.x;
    const int ks = blockIdx.y;
    const int t  = threadIdx.x;

    if (t < 128) prow[t] = pooled[(size_t)c * FDIM + ks * 128 + t];
    __syncthreads();

    float a = (ks == 0) ? bo[t] : 0.f;
#pragma unroll 4
    for (int k = 0; k < 128; ++k)
        a = fmaf(prow[k], Wo[(size_t)(ks * 128 + k) * ODIM + t], a);

    atomicAdd(&out[(size_t)c * ODIM + t], a);
}

// ---------------------------------------------------------------------------
extern "C" void kernel_launch(void* const* d_in, const int* in_sizes, int n_in,
                              void* d_out, int out_size, void* d_ws, size_t ws_size,
                              hipStream_t stream) {
    const float* x  = (const float*)d_in[0];
    // d_in[1] edge_index, d_in[2] batch: unused by the reference output
    const float* Wp = (const float*)d_in[3];
    const float* bp = (const float*)d_in[4];
    const float* We = (const float*)d_in[5];
    const float* be = (const float*)d_in[6];
    const float* Wo = (const float*)d_in[7];
    const float* bo = (const float*)d_in[8];
    float* out = (float*)d_out;

    const int N = in_sizes[0] / FDIM;   // 50000

    // workspace layout (floats):
    //   M      [0,      32768)
    //   colsum [32768,  32832)
    //   pooled [32832,  65600)
    //   s      [65600,  65600 + N*64)
    float* wsf    = (float*)d_ws;
    float* M      = wsf;
    float* colsum = wsf + 32768;
    float* pooled = wsf + 32832;
    float* s      = wsf + 65600;

    // zero accumulators (ws and out are re-poisoned before every call)
    hipMemsetAsync(d_ws, 0, (size_t)65600 * sizeof(float), stream);
    hipMemsetAsync(d_out, 0, (size_t)out_size * sizeof(float), stream);

    const int blocksA = (N + 63) / 64;
    kA<<<blocksA, 256, 0, stream>>>(x, Wp, bp, s, colsum, N);

    const int rch = (N + NCHUNKS - 1) / NCHUNKS;
    kB<<<dim3(NCHUNKS, FDIM / 64), 256, 0, stream>>>(x, s, M, N, rch);

    kC1<<<dim3(CDIM, 4), 256, 0, stream>>>(M, colsum, We, be, pooled);
    kC2<<<dim3(CDIM, 4), 256, 0, stream>>>(pooled, Wo, bo, out);
}

// Round 2
// 364.696 us; speedup vs baseline: 1.0370x; 1.0370x over previous
//
#include <hip/hip_runtime.h>
#include <hip/hip_bf16.h>

typedef __attribute__((ext_vector_type(8))) short short8;
typedef __attribute__((ext_vector_type(4))) float floatx4;

#define FDIM 512
#define CDIM 64
#define ODIM 256

// round-to-nearest-even fp32 -> bf16
__device__ __forceinline__ ushort f2bf(float f) {
    union { float f; unsigned u; } v; v.f = f;
    unsigned r = v.u + 0x7FFFu + ((v.u >> 16) & 1u);
    return (ushort)(r >> 16);
}

// ---------------- WpT[c][f] = bf16(Wp[f][c]) (64 KB, L2-resident) ----------
__global__ __launch_bounds__(256) void kWpT(const float* __restrict__ Wp,
                                            ushort* __restrict__ WpT) {
    int g = blockIdx.x * 256 + threadIdx.x;   // 0..32767
    int f = g >> 6, c = g & 63;
    WpT[c * FDIM + f] = f2bf(Wp[f * CDIM + c]);  // coalesced read, scattered 2B write
}

// ---------------- Fused: softmax(x Wp + bp) then M += s^T x ----------------
// 64 rows/block, 256 threads (4 waves). MFMA 16x16x32 bf16.
// Frag layouts (HW-verified per guide):
//   A: A[m=lane&15][k=quad*8+j]   B: B[k=quad*8+j][n=lane&15]
//   D: col(n)=lane&15, row(m)=quad*4+reg
__global__ __launch_bounds__(256, 3) void kFused(
        const float* __restrict__ x, const ushort* __restrict__ WpT,
        const float* __restrict__ bp, float* __restrict__ M,
        float* __restrict__ colsum, int N) {
    __shared__ ushort xs[64][136];   // x k-tile bf16 [row][128f + 8 pad] (17.4 KB)
    __shared__ ushort sT[64][72];    // s^T [c][row + 8 pad]              (9.2 KB)
    __shared__ float red1[64][4];
    __shared__ float red2[64][4];

    const int t    = threadIdx.x;
    const int w    = t >> 6;         // wave id = c-tile (phase1) / f-quadrant (phase2)
    const int lane = t & 63;
    const int l16  = lane & 15;
    const int q    = lane >> 4;
    const int row0 = blockIdx.x * 64;

    // ---- A-frags for phase 1: Wp^T, full K=512 held in 64 VGPRs ----
    short8 aw[16];
    {
        const ushort* base = WpT + (size_t)(16 * w + l16) * FDIM + q * 8;
#pragma unroll
        for (int ks = 0; ks < 16; ++ks)
            aw[ks] = *(const short8*)(base + ks * 32);
    }

    floatx4 acc1[4];
#pragma unroll
    for (int rt = 0; rt < 4; ++rt) acc1[rt] = (floatx4){0.f, 0.f, 0.f, 0.f};

    // ---- Phase 1: logits^T[c][row] = Wp^T x^T, k-tiled over f ----
    for (int kb = 0; kb < 4; ++kb) {
        __syncthreads();
#pragma unroll
        for (int i = 0; i < 8; ++i) {           // stage 64 x 128 fp32 -> bf16 LDS
            int v  = t + i * 256;               // 0..2047
            int r  = v >> 5;                    // 0..63
            int c4 = (v & 31) << 2;             // 0..124
            floatx4 val = (floatx4){0.f, 0.f, 0.f, 0.f};
            if (row0 + r < N)
                val = *(const floatx4*)(x + (size_t)(row0 + r) * FDIM + kb * 128 + c4);
            uint2 pk;
            pk.x = (unsigned)f2bf(val[0]) | ((unsigned)f2bf(val[1]) << 16);
            pk.y = (unsigned)f2bf(val[2]) | ((unsigned)f2bf(val[3]) << 16);
            *(uint2*)&xs[r][c4] = pk;
        }
        __syncthreads();
#pragma unroll
        for (int ki = 0; ki < 4; ++ki) {
#pragma unroll
            for (int rt = 0; rt < 4; ++rt) {
                short8 b = *(const short8*)&xs[16 * rt + l16][ki * 32 + q * 8];
                acc1[rt] = __builtin_amdgcn_mfma_f32_16x16x32_bf16(
                    aw[kb * 4 + ki], b, acc1[rt], 0, 0, 0);
            }
        }
    }

    // ---- softmax over c (per row); lane holds c = 16w+4q+reg, row = 16rt+l16 ----
    float bpv[4];
#pragma unroll
    for (int reg = 0; reg < 4; ++reg) bpv[reg] = bp[16 * w + 4 * q + reg];

    float lg[4][4], rmax[4], rsuminv[4];
#pragma unroll
    for (int rt = 0; rt < 4; ++rt) {
#pragma unroll
        for (int reg = 0; reg < 4; ++reg) lg[rt][reg] = acc1[rt][reg] + bpv[reg];
        float m = fmaxf(fmaxf(lg[rt][0], lg[rt][1]), fmaxf(lg[rt][2], lg[rt][3]));
        m = fmaxf(m, __shfl_xor(m, 16));
        m = fmaxf(m, __shfl_xor(m, 32));
        if (lane < 16) red1[16 * rt + lane][w] = m;   // per-wave partial max
    }
    __syncthreads();
#pragma unroll
    for (int rt = 0; rt < 4; ++rt)
        rmax[rt] = fmaxf(fmaxf(red1[16 * rt + l16][0], red1[16 * rt + l16][1]),
                         fmaxf(red1[16 * rt + l16][2], red1[16 * rt + l16][3]));
#pragma unroll
    for (int rt = 0; rt < 4; ++rt) {
        float p = 0.f;
#pragma unroll
        for (int reg = 0; reg < 4; ++reg) {
            float e = __expf(lg[rt][reg] - rmax[rt]);
            lg[rt][reg] = e; p += e;
        }
        p += __shfl_xor(p, 16);
        p += __shfl_xor(p, 32);
        if (lane < 16) red2[16 * rt + lane][w] = p;
    }
    __syncthreads();
#pragma unroll
    for (int rt = 0; rt < 4; ++rt)
        rsuminv[rt] = 1.0f / (red2[16 * rt + l16][0] + red2[16 * rt + l16][1] +
                              red2[16 * rt + l16][2] + red2[16 * rt + l16][3]);

    float csp[4] = {0.f, 0.f, 0.f, 0.f};
#pragma unroll
    for (int rt = 0; rt < 4; ++rt) {
        bool valid = (row0 + 16 * rt + l16) < N;
#pragma unroll
        for (int reg = 0; reg < 4; ++reg) {
            float s = valid ? lg[rt][reg] * rsuminv[rt] : 0.f;
            sT[16 * w + 4 * q + reg][16 * rt + l16] = f2bf(s);
            csp[reg] += s;
        }
    }
#pragma unroll
    for (int reg = 0; reg < 4; ++reg) {       // colsum[c] += sum over 64 rows
        float v = csp[reg];
        v += __shfl_xor(v, 1); v += __shfl_xor(v, 2);
        v += __shfl_xor(v, 4); v += __shfl_xor(v, 8);
        if (l16 == 0) atomicAdd(colsum + 16 * w + 4 * q + reg, v);
    }
    __syncthreads();   // sT visible to all waves

    // ---- Phase 2: M[c][f] += s^T x ; wave w covers f in [128w, 128w+128) ----
    short8 as[2][4];   // A-frags from sT, reused across f-chunks
#pragma unroll
    for (int ks = 0; ks < 2; ++ks)
#pragma unroll
        for (int mt = 0; mt < 4; ++mt)
            as[ks][mt] = *(const short8*)&sT[16 * mt + l16][ks * 32 + q * 8];

#pragma unroll 1
    for (int ch = 0; ch < 4; ++ch) {
        const int f0 = 128 * w + 32 * ch;
        floatx4 acc2[4][2];
#pragma unroll
        for (int mt = 0; mt < 4; ++mt)
#pragma unroll
            for (int nt = 0; nt < 2; ++nt) acc2[mt][nt] = (floatx4){0.f, 0.f, 0.f, 0.f};

#pragma unroll
        for (int ks = 0; ks < 2; ++ks) {
            short8 bx[2];
#pragma unroll
            for (int nt = 0; nt < 2; ++nt) {
                const int rbase = row0 + ks * 32 + q * 8;
                const float* gp = x + (size_t)rbase * FDIM + f0 + 16 * nt + l16;
                short8 bb;
#pragma unroll
                for (int i = 0; i < 8; ++i) {   // L2-hot re-read of own tile
                    float v = 0.f;
                    if (rbase + i < N) v = gp[(size_t)i * FDIM];
                    bb[i] = (short)f2bf(v);
                }
                bx[nt] = bb;
            }
#pragma unroll
            for (int mt = 0; mt < 4; ++mt)
#pragma unroll
                for (int nt = 0; nt < 2; ++nt)
                    acc2[mt][nt] = __builtin_amdgcn_mfma_f32_16x16x32_bf16(
                        as[ks][mt], bx[nt], acc2[mt][nt], 0, 0, 0);
        }
#pragma unroll
        for (int mt = 0; mt < 4; ++mt)
#pragma unroll
            for (int nt = 0; nt < 2; ++nt)
#pragma unroll
                for (int reg = 0; reg < 4; ++reg)
                    atomicAdd(M + (size_t)(16 * mt + 4 * q + reg) * FDIM + f0 + 16 * nt + l16,
                              acc2[mt][nt][reg]);
    }
}

// ---------------- pooled = M We + colsum (outer) be  (fp32) ----------------
__global__ __launch_bounds__(256) void kC1(const float* __restrict__ M,
                                           const float* __restrict__ colsum,
                                           const float* __restrict__ We,
                                           const float* __restrict__ be,
                                           float* __restrict__ pooled) {
    __shared__ float mrow[128];
    const int c = blockIdx.x, ks = blockIdx.y, t = threadIdx.x;
    if (t < 128) mrow[t] = M[(size_t)c * FDIM + ks * 128 + t];
    __syncthreads();
    float a0 = 0.f, a1 = 0.f;
    if (ks == 0) {
        float cs = colsum[c];
        a0 = cs * be[t];
        a1 = cs * be[t + 256];
    }
#pragma unroll 4
    for (int k = 0; k < 128; ++k) {
        float m = mrow[k];
        const float* wrow = We + (size_t)(ks * 128 + k) * FDIM;
        a0 = fmaf(m, wrow[t], a0);
        a1 = fmaf(m, wrow[t + 256], a1);
    }
    atomicAdd(&pooled[(size_t)c * FDIM + t], a0);
    atomicAdd(&pooled[(size_t)c * FDIM + t + 256], a1);
}

// ---------------- out = pooled Wo + bo  (fp32) -----------------------------
__global__ __launch_bounds__(256) void kC2(const float* __restrict__ pooled,
                                           const float* __restrict__ Wo,
                                           const float* __restrict__ bo,
                                           float* __restrict__ out) {
    __shared__ float prow[128];
    const int c = blockIdx.x, ks = blockIdx.y, t = threadIdx.x;
    if (t < 128) prow[t] = pooled[(size_t)c * FDIM + ks * 128 + t];
    __syncthreads();
    float a = (ks == 0) ? bo[t] : 0.f;
#pragma unroll 4
    for (int k = 0; k < 128; ++k)
        a = fmaf(prow[k], Wo[(size_t)(ks * 128 + k) * ODIM + t], a);
    atomicAdd(&out[(size_t)c * ODIM + t], a);
}

// ---------------------------------------------------------------------------
extern "C" void kernel_launch(void* const* d_in, const int* in_sizes, int n_in,
                              void* d_out, int out_size, void* d_ws, size_t ws_size,
                              hipStream_t stream) {
    const float* x  = (const float*)d_in[0];
    // d_in[1] edge_index, d_in[2] batch: unused by reference output
    const float* Wp = (const float*)d_in[3];
    const float* bp = (const float*)d_in[4];
    const float* We = (const float*)d_in[5];
    const float* be = (const float*)d_in[6];
    const float* Wo = (const float*)d_in[7];
    const float* bo = (const float*)d_in[8];
    float* out = (float*)d_out;

    const int N = in_sizes[0] / FDIM;   // 50000

    // ws layout: WpT (32768 ushort = 16384 floats) | M (32768 f) | colsum (64 f) | pooled (32768 f)
    float*  wsf    = (float*)d_ws;
    ushort* WpT    = (ushort*)d_ws;
    float*  M      = wsf + 16384;
    float*  colsum = wsf + 16384 + 32768;
    float*  pooled = wsf + 16384 + 32768 + 64;

    hipMemsetAsync((char*)d_ws + 65536, 0, (size_t)(32768 + 64 + 32768) * 4, stream);
    hipMemsetAsync(d_out, 0, (size_t)out_size * 4, stream);

    kWpT<<<128, 256, 0, stream>>>(Wp, WpT);
    kFused<<<(N + 63) / 64, 256, 0, stream>>>(x, WpT, bp, M, colsum, N);
    kC1<<<dim3(CDIM, 4), 256, 0, stream>>>(M, colsum, We, be, pooled);
    kC2<<<dim3(CDIM, 4), 256, 0, stream>>>(pooled, Wo, bo, out);
}

// Round 3
// 310.708 us; speedup vs baseline: 1.2172x; 1.1738x over previous
//
#include <hip/hip_runtime.h>
#include <hip/hip_bf16.h>

typedef __attribute__((ext_vector_type(8))) short short8;
typedef __attribute__((ext_vector_type(4))) float floatx4;

#define FDIM 512
#define CDIM 64
#define ODIM 256
#define XS_STRIDE 520   // 512 + 8 pad (keeps 16B alignment for b128 rows)
#define ST_STRIDE 72

// round-to-nearest-even fp32 -> bf16
__device__ __forceinline__ ushort f2bf(float f) {
    union { float f; unsigned u; } v; v.f = f;
    unsigned r = v.u + 0x7FFFu + ((v.u >> 16) & 1u);
    return (ushort)(r >> 16);
}
__device__ __forceinline__ float bf2f(unsigned hi16) {
    union { unsigned u; float f; } v; v.u = hi16 << 16; return v.f;
}

// ---------------- WpT[c][f] = bf16(Wp[f][c]) (64 KB, L2-resident) ----------
__global__ __launch_bounds__(256) void kWpT(const float* __restrict__ Wp,
                                            ushort* __restrict__ WpT) {
    int g = blockIdx.x * 256 + threadIdx.x;   // 0..32767
    int f = g >> 6, c = g & 63;
    WpT[c * FDIM + f] = f2bf(Wp[f * CDIM + c]);
}

// ---------------- Fused persistent kernel ---------------------------------
// Work-steals 64-row tiles. Per tile: stage x (bf16) to LDS; MFMA logits^T;
// softmax -> sT (LDS); MFMA M += s^T x with M accumulated in VGPRs across
// ALL tiles; single flush per block at the end (bf16 partial, no atomics).
__global__ __launch_bounds__(256, 2) void kFused(
        const float* __restrict__ x, const ushort* __restrict__ WpT,
        const float* __restrict__ bp, float* __restrict__ M,
        float* __restrict__ colsum, ushort* __restrict__ part,
        int* __restrict__ ctr, int N, int nTiles, int atomicFlush) {
    __shared__ ushort xs[64][XS_STRIDE];   // 66.5 KB  x tile bf16 [row][f]
    __shared__ ushort sT[64][ST_STRIDE];   //  9.2 KB  s^T [c][row]
    __shared__ float red1[64][4];
    __shared__ float red2[64][4];
    __shared__ int sj;

    const int t    = threadIdx.x;
    const int w    = t >> 6;          // wave: phase1 c-tile / phase2 f-slice
    const int lane = t & 63;
    const int l16  = lane & 15;
    const int q    = lane >> 4;

    // persistent accumulators: M slice [4 c-tiles][8 f-tiles] (128 VGPRs)
    floatx4 acc[4][8];
#pragma unroll
    for (int mt = 0; mt < 4; ++mt)
#pragma unroll
        for (int nt = 0; nt < 8; ++nt) acc[mt][nt] = (floatx4){0.f, 0.f, 0.f, 0.f};
    float csp[4] = {0.f, 0.f, 0.f, 0.f};

    float bpv[4];
#pragma unroll
    for (int reg = 0; reg < 4; ++reg) bpv[reg] = bp[16 * w + 4 * q + reg];

    const ushort* wbase = WpT + (size_t)(16 * w + l16) * FDIM + q * 8;

    for (;;) {
        if (t == 0) sj = atomicAdd(ctr, 1);
        __syncthreads();              // publishes sj; guards xs vs prev phase-2
        const int tile = sj;
        if (tile >= nTiles) break;
        const int row0 = tile * 64;

        // ---- stage x tile: 64x512 fp32 -> bf16 LDS (coalesced float4) ----
#pragma unroll 8
        for (int i = 0; i < 32; ++i) {
            int v  = i * 256 + t;
            int r  = v >> 7;               // 0..63
            int f4 = (v & 127) << 2;       // 0..508
            floatx4 val = (floatx4){0.f, 0.f, 0.f, 0.f};
            if (row0 + r < N)
                val = *(const floatx4*)(x + (size_t)(row0 + r) * FDIM + f4);
            uint2 pk;
            pk.x = (unsigned)f2bf(val[0]) | ((unsigned)f2bf(val[1]) << 16);
            pk.y = (unsigned)f2bf(val[2]) | ((unsigned)f2bf(val[3]) << 16);
            *(uint2*)&xs[r][f4] = pk;
        }
        __syncthreads();

        // ---- phase 1: logitsT[c][row], A=WpT (global, L2-hot), B=xs ----
        floatx4 acc1[4];
#pragma unroll
        for (int rt = 0; rt < 4; ++rt) acc1[rt] = (floatx4){0.f, 0.f, 0.f, 0.f};
        short8 a_cur[4], a_nxt[4];
#pragma unroll
        for (int kk = 0; kk < 4; ++kk) a_cur[kk] = *(const short8*)(wbase + kk * 32);
#pragma unroll
        for (int kb = 0; kb < 4; ++kb) {
            if (kb < 3) {
#pragma unroll
                for (int kk = 0; kk < 4; ++kk)
                    a_nxt[kk] = *(const short8*)(wbase + ((kb + 1) * 4 + kk) * 32);
            }
#pragma unroll
            for (int ki = 0; ki < 4; ++ki) {
#pragma unroll
                for (int rt = 0; rt < 4; ++rt) {
                    short8 b = *(const short8*)&xs[16 * rt + l16][kb * 128 + ki * 32 + q * 8];
                    acc1[rt] = __builtin_amdgcn_mfma_f32_16x16x32_bf16(
                        a_cur[ki], b, acc1[rt], 0, 0, 0);
                }
            }
#pragma unroll
            for (int kk = 0; kk < 4; ++kk) a_cur[kk] = a_nxt[kk];
        }

        // ---- softmax over c per row (lane: c=16w+4q+reg, row=16rt+l16) ----
        float lg[4][4], rmax[4], rsuminv[4];
#pragma unroll
        for (int rt = 0; rt < 4; ++rt) {
#pragma unroll
            for (int reg = 0; reg < 4; ++reg) lg[rt][reg] = acc1[rt][reg] + bpv[reg];
            float m = fmaxf(fmaxf(lg[rt][0], lg[rt][1]), fmaxf(lg[rt][2], lg[rt][3]));
            m = fmaxf(m, __shfl_xor(m, 16));
            m = fmaxf(m, __shfl_xor(m, 32));
            if (lane < 16) red1[16 * rt + lane][w] = m;
        }
        __syncthreads();
#pragma unroll
        for (int rt = 0; rt < 4; ++rt)
            rmax[rt] = fmaxf(fmaxf(red1[16 * rt + l16][0], red1[16 * rt + l16][1]),
                             fmaxf(red1[16 * rt + l16][2], red1[16 * rt + l16][3]));
#pragma unroll
        for (int rt = 0; rt < 4; ++rt) {
            float p = 0.f;
#pragma unroll
            for (int reg = 0; reg < 4; ++reg) {
                float e = __expf(lg[rt][reg] - rmax[rt]);
                lg[rt][reg] = e; p += e;
            }
            p += __shfl_xor(p, 16);
            p += __shfl_xor(p, 32);
            if (lane < 16) red2[16 * rt + lane][w] = p;
        }
        __syncthreads();
#pragma unroll
        for (int rt = 0; rt < 4; ++rt)
            rsuminv[rt] = 1.0f / (red2[16 * rt + l16][0] + red2[16 * rt + l16][1] +
                                  red2[16 * rt + l16][2] + red2[16 * rt + l16][3]);
#pragma unroll
        for (int rt = 0; rt < 4; ++rt) {
            bool valid = (row0 + 16 * rt + l16) < N;
#pragma unroll
            for (int reg = 0; reg < 4; ++reg) {
                float s = valid ? lg[rt][reg] * rsuminv[rt] : 0.f;
                sT[16 * w + 4 * q + reg][16 * rt + l16] = f2bf(s);
                csp[reg] += s;
            }
        }
        __syncthreads();   // sT ready (xs still intact)

        // ---- phase 2: acc += s^T x over this tile's 64 rows ----
        short8 as_[2][4];
#pragma unroll
        for (int ks = 0; ks < 2; ++ks)
#pragma unroll
            for (int mt = 0; mt < 4; ++mt)
                as_[ks][mt] = *(const short8*)&sT[16 * mt + l16][ks * 32 + q * 8];
#pragma unroll
        for (int nt = 0; nt < 8; ++nt) {
            const int f = 128 * w + 16 * nt + l16;
            short8 b0, b1;
#pragma unroll
            for (int j = 0; j < 8; ++j) {
                b0[j] = (short)xs[8 * q + j][f];
                b1[j] = (short)xs[32 + 8 * q + j][f];
            }
#pragma unroll
            for (int mt = 0; mt < 4; ++mt) {
                acc[mt][nt] = __builtin_amdgcn_mfma_f32_16x16x32_bf16(
                    as_[0][mt], b0, acc[mt][nt], 0, 0, 0);
                acc[mt][nt] = __builtin_amdgcn_mfma_f32_16x16x32_bf16(
                    as_[1][mt], b1, acc[mt][nt], 0, 0, 0);
            }
        }
    }

    // ---- flush colsum (one atomic per c per block) ----
#pragma unroll
    for (int reg = 0; reg < 4; ++reg) {
        float v = csp[reg];
        v += __shfl_xor(v, 1); v += __shfl_xor(v, 2);
        v += __shfl_xor(v, 4); v += __shfl_xor(v, 8);
        if (l16 == 0) atomicAdd(colsum + 16 * w + 4 * q + reg, v);
    }

    // ---- flush M slice ----
    if (!atomicFlush) {
        ushort* dst = part + (size_t)blockIdx.x * (CDIM * FDIM);
#pragma unroll
        for (int mt = 0; mt < 4; ++mt)
#pragma unroll
            for (int nt = 0; nt < 8; ++nt)
#pragma unroll
                for (int reg = 0; reg < 4; ++reg)
                    dst[(size_t)(16 * mt + 4 * q + reg) * FDIM + 128 * w + 16 * nt + l16] =
                        f2bf(acc[mt][nt][reg]);
    } else {
#pragma unroll
        for (int mt = 0; mt < 4; ++mt)
#pragma unroll
            for (int nt = 0; nt < 8; ++nt)
#pragma unroll
                for (int reg = 0; reg < 4; ++reg)
                    atomicAdd(M + (size_t)(16 * mt + 4 * q + reg) * FDIM + 128 * w + 16 * nt + l16,
                              acc[mt][nt][reg]);
    }
}

// ---------------- reduce P bf16 partials -> fp32 M -------------------------
__global__ __launch_bounds__(256) void kRed(const ushort* __restrict__ part,
                                            float* __restrict__ M, int P, int Pch) {
    const int idx = blockIdx.x * 256 + threadIdx.x;   // 0..16383, 2 cf each
    const int p0 = blockIdx.y * Pch;
    const int p1 = min(p0 + Pch, P);
    const ushort* base = part + (size_t)idx * 2;
    float s0 = 0.f, s1 = 0.f;
#pragma unroll 4
    for (int p = p0; p < p1; ++p) {
        unsigned v = *(const unsigned*)(base + (size_t)p * (CDIM * FDIM));
        s0 += bf2f(v & 0xffffu);
        s1 += bf2f(v >> 16);
    }
    atomicAdd(&M[idx * 2], s0);
    atomicAdd(&M[idx * 2 + 1], s1);
}

// ---------------- pooled = M We + colsum (outer) be  (fp32) ----------------
__global__ __launch_bounds__(256) void kC1(const float* __restrict__ M,
                                           const float* __restrict__ colsum,
                                           const float* __restrict__ We,
                                           const float* __restrict__ be,
                                           float* __restrict__ pooled) {
    __shared__ float mrow[128];
    const int c = blockIdx.x, ks = blockIdx.y, t = threadIdx.x;
    if (t < 128) mrow[t] = M[(size_t)c * FDIM + ks * 128 + t];
    __syncthreads();
    float a0 = 0.f, a1 = 0.f;
    if (ks == 0) {
        float cs = colsum[c];
        a0 = cs * be[t];
        a1 = cs * be[t + 256];
    }
#pragma unroll 4
    for (int k = 0; k < 128; ++k) {
        float m = mrow[k];
        const float* wrow = We + (size_t)(ks * 128 + k) * FDIM;
        a0 = fmaf(m, wrow[t], a0);
        a1 = fmaf(m, wrow[t + 256], a1);
    }
    atomicAdd(&pooled[(size_t)c * FDIM + t], a0);
    atomicAdd(&pooled[(size_t)c * FDIM + t + 256], a1);
}

// ---------------- out = pooled Wo + bo  (fp32) -----------------------------
__global__ __launch_bounds__(256) void kC2(const float* __restrict__ pooled,
                                           const float* __restrict__ Wo,
                                           const float* __restrict__ bo,
                                           float* __restrict__ out) {
    __shared__ float prow[128];
    const int c = blockIdx.x, ks = blockIdx.y, t = threadIdx.x;
    if (t < 128) prow[t] = pooled[(size_t)c * FDIM + ks * 128 + t];
    __syncthreads();
    float a = (ks == 0) ? bo[t] : 0.f;
#pragma unroll 4
    for (int k = 0; k < 128; ++k)
        a = fmaf(prow[k], Wo[(size_t)(ks * 128 + k) * ODIM + t], a);
    atomicAdd(&out[(size_t)c * ODIM + t], a);
}

// ---------------------------------------------------------------------------
extern "C" void kernel_launch(void* const* d_in, const int* in_sizes, int n_in,
                              void* d_out, int out_size, void* d_ws, size_t ws_size,
                              hipStream_t stream) {
    const float* x  = (const float*)d_in[0];
    // d_in[1] edge_index, d_in[2] batch: unused by reference output
    const float* Wp = (const float*)d_in[3];
    const float* bp = (const float*)d_in[4];
    const float* We = (const float*)d_in[5];
    const float* be = (const float*)d_in[6];
    const float* Wo = (const float*)d_in[7];
    const float* bo = (const float*)d_in[8];
    float* out = (float*)d_out;

    const int N = in_sizes[0] / FDIM;         // 50000
    const int nTiles = (N + 63) / 64;         // 782

    // ws byte layout:
    //   [0,      65536)  WpT bf16
    //   [65536, 196608)  M fp32
    //   [196608,196864)  colsum
    //   [196864,197120)  work-steal counter
    //   [197120,328192)  pooled fp32
    //   [331776, ...)    bf16 M partials, 64 KB each
    char* wsb = (char*)d_ws;
    ushort* WpT    = (ushort*)(wsb);
    float*  M      = (float*)(wsb + 65536);
    float*  colsum = (float*)(wsb + 196608);
    int*    ctr    = (int*)  (wsb + 196864);
    float*  pooled = (float*)(wsb + 197120);
    const size_t PART_OFF = 331776;
    ushort* part   = (ushort*)(wsb + PART_OFF);

    int P = 0;
    if (ws_size > PART_OFF + 65536)
        P = (int)(((ws_size - PART_OFF) / 65536) < 512 ? (ws_size - PART_OFF) / 65536 : 512);
    const int atomicFlush = (P < 64) ? 1 : 0;
    const int grid = atomicFlush ? 512 : P;

    // zero M+colsum+ctr+pooled in one shot, and out
    hipMemsetAsync(wsb + 65536, 0, 328192 - 65536, stream);
    hipMemsetAsync(d_out, 0, (size_t)out_size * 4, stream);

    kWpT<<<128, 256, 0, stream>>>(Wp, WpT);
    kFused<<<grid, 256, 0, stream>>>(x, WpT, bp, M, colsum, part, ctr, N, nTiles, atomicFlush);
    if (!atomicFlush)
        kRed<<<dim3(64, 4), 256, 0, stream>>>(part, M, P, (P + 3) / 4);
    kC1<<<dim3(CDIM, 4), 256, 0, stream>>>(M, colsum, We, be, pooled);
    kC2<<<dim3(CDIM, 4), 256, 0, stream>>>(pooled, Wo, bo, out);
}

// Round 4
// 298.038 us; speedup vs baseline: 1.2689x; 1.0425x over previous
//
#include <hip/hip_runtime.h>
#include <hip/hip_bf16.h>

typedef __attribute__((ext_vector_type(8))) short short8;
typedef __attribute__((ext_vector_type(4))) float floatx4;
typedef __attribute__((ext_vector_type(4))) unsigned uint4v;

#define FDIM 512
#define CDIM 64
#define ODIM 256
#define XSS 520      // xs row stride (ushort): 512 + 8 pad
#define STS 72       // sT row stride
#define MAXP 256

// round-to-nearest-even fp32 -> bf16
__device__ __forceinline__ ushort f2bf(float f) {
    union { float f; unsigned u; } v; v.f = f;
    unsigned r = v.u + 0x7FFFu + ((v.u >> 16) & 1u);
    return (ushort)(r >> 16);
}
__device__ __forceinline__ float bf2f(unsigned hi16) {
    union { unsigned u; float f; } v; v.u = hi16 << 16; return v.f;
}

// ---------------- WpT[c][f] = bf16(Wp[f][c]) (64 KB, one-shot) -------------
__global__ __launch_bounds__(256) void kWpT(const float* __restrict__ Wp,
                                            ushort* __restrict__ WpT) {
    int g = blockIdx.x * 256 + threadIdx.x;   // 0..32767
    int f = g >> 6, c = g & 63;
    WpT[c * FDIM + f] = f2bf(Wp[f * CDIM + c]);
}

// ---------------- Fused persistent kernel (512 thr = 8 waves) --------------
// Work-steals 64-row tiles. Per tile: stage x->LDS bf16; MFMA logits^T;
// cross-wave softmax -> sT; MFMA M += s^T x into per-wave 64-reg acc.
// Flush once per block: acc -> LDS (bf16) -> coalesced uint4 store.
__global__ __launch_bounds__(512, 2) void kFused(
        const float* __restrict__ x, const ushort* __restrict__ WpT,
        const float* __restrict__ bp, float* __restrict__ colsum,
        ushort* __restrict__ part, int* __restrict__ ctr, int N, int nTiles) {
    __shared__ ushort xs[64][XSS];   // 66.6 KB x tile bf16 [row][f]
    __shared__ ushort sT[64][STS];   //  9.2 KB s^T [c][row]
    __shared__ float red1[64][4];
    __shared__ float red2[64][4];
    __shared__ int sj;

    const int t    = threadIdx.x;
    const int w    = t >> 6;        // 0..7
    const int lane = t & 63;
    const int l16  = lane & 15;
    const int q    = lane >> 4;
    const int ci   = w & 3;         // phase-1 c-tile (16 c)
    const int rg   = w >> 2;        // phase-1 row-group (rows 32rg..32rg+31)

    // persistent M slice: c 0..63 (mt), f in [64w,64w+64) (nt) -> 64 VGPRs
    floatx4 acc[4][4];
#pragma unroll
    for (int mt = 0; mt < 4; ++mt)
#pragma unroll
        for (int nt = 0; nt < 4; ++nt) acc[mt][nt] = (floatx4){0.f, 0.f, 0.f, 0.f};
    float csp[4] = {0.f, 0.f, 0.f, 0.f};

    float bpv[4];
#pragma unroll
    for (int reg = 0; reg < 4; ++reg) bpv[reg] = bp[16 * ci + 4 * q + reg];

    const ushort* wb = WpT + (size_t)(16 * ci + l16) * FDIM + q * 8;

    for (;;) {
        if (t == 0) sj = atomicAdd(ctr, 1);
        __syncthreads();             // publishes sj; guards xs vs prev phase-2
        const int tile = sj;
        if (tile >= nTiles) break;
        const int row0 = tile * 64;

        // ---- stage x tile: 64x512 fp32 -> bf16 LDS ----
#pragma unroll 4
        for (int i = 0; i < 16; ++i) {
            int v  = i * 512 + t;
            int r  = v >> 7;               // 0..63
            int f4 = (v & 127) << 2;       // 0..508
            floatx4 val = (floatx4){0.f, 0.f, 0.f, 0.f};
            if (row0 + r < N)
                val = *(const floatx4*)(x + (size_t)(row0 + r) * FDIM + f4);
            uint2 pk;
            pk.x = (unsigned)f2bf(val[0]) | ((unsigned)f2bf(val[1]) << 16);
            pk.y = (unsigned)f2bf(val[2]) | ((unsigned)f2bf(val[3]) << 16);
            *(uint2*)&xs[r][f4] = pk;
        }
        __syncthreads();

        // ---- phase 1: logitsT[16ci..+16][rows 32rg..+32], K=512 ----
        floatx4 acc1[2];
        acc1[0] = (floatx4){0.f, 0.f, 0.f, 0.f};
        acc1[1] = (floatx4){0.f, 0.f, 0.f, 0.f};
#pragma unroll
        for (int kb = 0; kb < 4; ++kb) {
            short8 af[4];
#pragma unroll
            for (int ki = 0; ki < 4; ++ki)
                af[ki] = *(const short8*)(wb + kb * 128 + ki * 32);
#pragma unroll
            for (int ki = 0; ki < 4; ++ki) {
#pragma unroll
                for (int rt = 0; rt < 2; ++rt) {
                    short8 b = *(const short8*)&xs[16 * (2 * rg + rt) + l16]
                                                  [kb * 128 + ki * 32 + q * 8];
                    acc1[rt] = __builtin_amdgcn_mfma_f32_16x16x32_bf16(
                        af[ki], b, acc1[rt], 0, 0, 0);
                }
            }
        }

        // ---- softmax over c per row; lane: c=16ci+4q+reg, row=16(2rg+rt)+l16 ----
        float lg[2][4], rmax[2], rsi[2];
#pragma unroll
        for (int rt = 0; rt < 2; ++rt) {
#pragma unroll
            for (int reg = 0; reg < 4; ++reg) lg[rt][reg] = acc1[rt][reg] + bpv[reg];
            float m = fmaxf(fmaxf(lg[rt][0], lg[rt][1]), fmaxf(lg[rt][2], lg[rt][3]));
            m = fmaxf(m, __shfl_xor(m, 16));
            m = fmaxf(m, __shfl_xor(m, 32));
            if (lane < 16) red1[16 * (2 * rg + rt) + lane][ci] = m;
        }
        __syncthreads();
#pragma unroll
        for (int rt = 0; rt < 2; ++rt) {
            const int row = 16 * (2 * rg + rt) + l16;
            rmax[rt] = fmaxf(fmaxf(red1[row][0], red1[row][1]),
                             fmaxf(red1[row][2], red1[row][3]));
        }
#pragma unroll
        for (int rt = 0; rt < 2; ++rt) {
            float p = 0.f;
#pragma unroll
            for (int reg = 0; reg < 4; ++reg) {
                float e = __expf(lg[rt][reg] - rmax[rt]);
                lg[rt][reg] = e; p += e;
            }
            p += __shfl_xor(p, 16);
            p += __shfl_xor(p, 32);
            if (lane < 16) red2[16 * (2 * rg + rt) + lane][ci] = p;
        }
        __syncthreads();
#pragma unroll
        for (int rt = 0; rt < 2; ++rt) {
            const int row = 16 * (2 * rg + rt) + l16;
            rsi[rt] = 1.0f / (red2[row][0] + red2[row][1] +
                              red2[row][2] + red2[row][3]);
        }
#pragma unroll
        for (int rt = 0; rt < 2; ++rt) {
            const int row = 16 * (2 * rg + rt) + l16;
            bool valid = (row0 + row) < N;
#pragma unroll
            for (int reg = 0; reg < 4; ++reg) {
                float s = valid ? lg[rt][reg] * rsi[rt] : 0.f;
                sT[16 * ci + 4 * q + reg][row] = f2bf(s);
                csp[reg] += s;
            }
        }
        __syncthreads();   // sT ready; xs still intact

        // ---- phase 2: acc += s^T x over this tile (K=64 rows) ----
        short8 as_[2][4];
#pragma unroll
        for (int ks = 0; ks < 2; ++ks)
#pragma unroll
            for (int mt = 0; mt < 4; ++mt)
                as_[ks][mt] = *(const short8*)&sT[16 * mt + l16][ks * 32 + q * 8];
#pragma unroll
        for (int nt = 0; nt < 4; ++nt) {
            const int f = 64 * w + 16 * nt + l16;
            short8 b0, b1;
#pragma unroll
            for (int j = 0; j < 8; ++j) {
                b0[j] = (short)xs[q * 8 + j][f];
                b1[j] = (short)xs[32 + q * 8 + j][f];
            }
#pragma unroll
            for (int mt = 0; mt < 4; ++mt) {
                acc[mt][nt] = __builtin_amdgcn_mfma_f32_16x16x32_bf16(
                    as_[0][mt], b0, acc[mt][nt], 0, 0, 0);
                acc[mt][nt] = __builtin_amdgcn_mfma_f32_16x16x32_bf16(
                    as_[1][mt], b1, acc[mt][nt], 0, 0, 0);
            }
        }
    }

    // ---- colsum: one atomic per c per wave-group ----
#pragma unroll
    for (int reg = 0; reg < 4; ++reg) {
        float v = csp[reg];
        v += __shfl_xor(v, 1); v += __shfl_xor(v, 2);
        v += __shfl_xor(v, 4); v += __shfl_xor(v, 8);
        if (l16 == 0) atomicAdd(colsum + 16 * ci + 4 * q + reg, v);
    }

    // ---- flush: acc -> xs (bf16, scatter in LDS) -> coalesced global ----
    ushort* xf = &xs[0][0];
#pragma unroll
    for (int mt = 0; mt < 4; ++mt)
#pragma unroll
        for (int nt = 0; nt < 4; ++nt)
#pragma unroll
            for (int reg = 0; reg < 4; ++reg)
                xf[(16 * mt + 4 * q + reg) * FDIM + 64 * w + 16 * nt + l16] =
                    f2bf(acc[mt][nt][reg]);
    __syncthreads();
    const uint4v* src = (const uint4v*)xf;
    uint4v* dst = (uint4v*)(part + (size_t)blockIdx.x * (CDIM * FDIM));
#pragma unroll
    for (int i = 0; i < 8; ++i)
        dst[i * 512 + t] = src[i * 512 + t];
}

// ---------------- epilogue: partials -> M -> pooled -> out -----------------
// 64 blocks (one per cluster c), 512 threads.
__global__ __launch_bounds__(512) void kC(const ushort* __restrict__ part,
                                          const float* __restrict__ colsum,
                                          const float* __restrict__ We,
                                          const float* __restrict__ be,
                                          const float* __restrict__ Wo,
                                          const float* __restrict__ bo,
                                          float* __restrict__ out, int P) {
    __shared__ float Mrow[512];
    __shared__ float pooled[512];
    __shared__ float halves[2][256];
    const int c = blockIdx.x, t = threadIdx.x;

    // A: M[c][t] = sum_p part[p][c][t]
    float sum = 0.f;
    const ushort* pp = part + (size_t)c * FDIM + t;
#pragma unroll 8
    for (int p = 0; p < P; ++p)
        sum += bf2f((unsigned)pp[(size_t)p * (CDIM * FDIM)]);
    Mrow[t] = sum;
    __syncthreads();

    // B: pooled[t] = colsum[c]*be[t] + sum_k Mrow[k]*We[k][t]
    float a = colsum[c] * be[t];
#pragma unroll 16
    for (int k = 0; k < FDIM; ++k)
        a = fmaf(Mrow[k], We[(size_t)k * FDIM + t], a);
    pooled[t] = a;
    __syncthreads();

    // C: out[c][o] = bo[o] + sum_k pooled[k]*Wo[k][o]  (k split in halves)
    const int o = t & 255, h = t >> 8;
    float b = 0.f;
#pragma unroll 16
    for (int kk = 0; kk < 256; ++kk) {
        int k = h * 256 + kk;
        b = fmaf(pooled[k], Wo[(size_t)k * ODIM + o], b);
    }
    halves[h][o] = b;
    __syncthreads();
    if (t < 256)
        out[(size_t)c * ODIM + t] = halves[0][t] + halves[1][t] + bo[t];
}

// ---------------------------------------------------------------------------
extern "C" void kernel_launch(void* const* d_in, const int* in_sizes, int n_in,
                              void* d_out, int out_size, void* d_ws, size_t ws_size,
                              hipStream_t stream) {
    const float* x  = (const float*)d_in[0];
    // d_in[1] edge_index, d_in[2] batch: unused by reference output
    const float* Wp = (const float*)d_in[3];
    const float* bp = (const float*)d_in[4];
    const float* We = (const float*)d_in[5];
    const float* be = (const float*)d_in[6];
    const float* Wo = (const float*)d_in[7];
    const float* bo = (const float*)d_in[8];
    float* out = (float*)d_out;

    const int N = in_sizes[0] / FDIM;         // 50000
    const int nTiles = (N + 63) / 64;         // 782

    // ws bytes: [0,65536) WpT | [65536,65792) colsum | [65792,65796) ctr
    //           [66560, 66560 + P*65536) bf16 M partials
    char*   wsb    = (char*)d_ws;
    ushort* WpT    = (ushort*)wsb;
    float*  colsum = (float*)(wsb + 65536);
    int*    ctr    = (int*)(wsb + 65792);
    const size_t PART_OFF = 66560;
    ushort* part   = (ushort*)(wsb + PART_OFF);

    size_t pcap = (ws_size > PART_OFF + 65536) ? (ws_size - PART_OFF) / 65536 : 1;
    int P = (int)(pcap < MAXP ? pcap : MAXP);
    if (P < 1) P = 1;

    hipMemsetAsync(wsb + 65536, 0, 1024, stream);   // colsum + ctr
    kWpT<<<128, 256, 0, stream>>>(Wp, WpT);
    kFused<<<P, 512, 0, stream>>>(x, WpT, bp, colsum, part, ctr, N, nTiles);
    kC<<<CDIM, 512, 0, stream>>>(part, colsum, We, be, Wo, bo, out, P);
}

// Round 5
// 257.580 us; speedup vs baseline: 1.4682x; 1.1571x over previous
//
#include <hip/hip_runtime.h>
#include <hip/hip_bf16.h>

typedef __attribute__((ext_vector_type(8))) short short8;
typedef __attribute__((ext_vector_type(4))) float floatx4;
typedef __attribute__((ext_vector_type(4))) unsigned uint4v;

#define FDIM 512
#define CDIM 64
#define ODIM 256
#define XSS 520                    // xs row stride (ushort), rows 16B-aligned
#define STS 72                     // sT row stride
// column swizzle: element (r,f) stored at column f ^ (((r>>3)&3)<<4).
// Makes phase-2 column gathers conflict-free (q-groups hit disjoint banks).
#define XSW(r, f) ((f) ^ ((((r) >> 3) & 3) << 4))

// round-to-nearest-even fp32 -> bf16
__device__ __forceinline__ ushort f2bf(float f) {
    union { float f; unsigned u; } v; v.f = f;
    unsigned r = v.u + 0x7FFFu + ((v.u >> 16) & 1u);
    return (ushort)(r >> 16);
}
__device__ __forceinline__ float bf2f(unsigned hi16) {
    union { unsigned u; float f; } v; v.u = hi16 << 16; return v.f;
}

// ---------------- WpT[c][f] = bf16(Wp[f][c]) (64 KB, L2/L3-resident) -------
__global__ __launch_bounds__(256) void kWpT(const float* __restrict__ Wp,
                                            ushort* __restrict__ WpT) {
    int g = blockIdx.x * 256 + threadIdx.x;   // 0..32767
    int f = g >> 6, c = g & 63;
    WpT[c * FDIM + f] = f2bf(Wp[f * CDIM + c]);
}

// ---------------- Fused: per 64-row tile, s=softmax(xWp+bp); M_p = s^T x ---
// Grid = P blocks; block b handles tiles b, b+P, ... (normally P=nTiles -> 1
// tile/block). 512 threads = 8 waves. Per-block output: bf16 partial M
// [64c][512f] + fp32 colsum partial [64c]. No global atomics.
__global__ __launch_bounds__(512, 2) void kFused(
        const float* __restrict__ x, const ushort* __restrict__ WpT,
        const float* __restrict__ bp, ushort* __restrict__ part,
        float* __restrict__ cpart, int N, int nTiles, int P) {
    __shared__ ushort xs[64][XSS];   // 66.6 KB swizzled x tile bf16
    __shared__ ushort sT[64][STS];   //  9.2 KB s^T [c][row]
    __shared__ float red1[64][4];
    __shared__ float red2[64][4];

    const int t    = threadIdx.x;
    const int w    = t >> 6;        // 0..7
    const int lane = t & 63;
    const int l16  = lane & 15;
    const int q    = lane >> 4;
    const int ci   = w & 3;         // phase-1 c-tile (16 c)
    const int rg   = w >> 2;        // phase-1 row-group (rows 32rg..32rg+31)

    // persistent M slice: c 0..63 (mt), f in [64w,64w+64) (nt) -> 64 VGPRs
    floatx4 acc[4][4];
#pragma unroll
    for (int mt = 0; mt < 4; ++mt)
#pragma unroll
        for (int nt = 0; nt < 4; ++nt) acc[mt][nt] = (floatx4){0.f, 0.f, 0.f, 0.f};
    float csp[4] = {0.f, 0.f, 0.f, 0.f};

    float bpv[4];
#pragma unroll
    for (int reg = 0; reg < 4; ++reg) bpv[reg] = bp[16 * ci + 4 * q + reg];

    const ushort* wb = WpT + (size_t)(16 * ci + l16) * FDIM + q * 8;
    const int permA0 = (((l16 >> 3) & 1)) << 4;          // rt=0
    const int permA1 = ((2 + ((l16 >> 3) & 1)) & 3) << 4; // rt=1

    for (int tile = blockIdx.x; tile < nTiles; tile += P) {
        __syncthreads();             // guard xs vs previous iteration phase-2
        const int row0 = tile * 64;

        // ---- stage x tile: 64x512 fp32 -> bf16 LDS, 8 loads in flight ----
#pragma unroll
        for (int half = 0; half < 2; ++half) {
            floatx4 vv[8];
#pragma unroll
            for (int j = 0; j < 8; ++j) {
                int v = (half * 8 + j) * 512 + t;
                int r = v >> 7;
                int f4 = (v & 127) << 2;
                vv[j] = (floatx4){0.f, 0.f, 0.f, 0.f};
                if (row0 + r < N)
                    vv[j] = *(const floatx4*)(x + (size_t)(row0 + r) * FDIM + f4);
            }
#pragma unroll
            for (int j = 0; j < 8; ++j) {
                int v = (half * 8 + j) * 512 + t;
                int r = v >> 7;
                int f4 = (v & 127) << 2;
                uint2 pk;
                pk.x = (unsigned)f2bf(vv[j][0]) | ((unsigned)f2bf(vv[j][1]) << 16);
                pk.y = (unsigned)f2bf(vv[j][2]) | ((unsigned)f2bf(vv[j][3]) << 16);
                *(uint2*)&xs[r][XSW(r, f4)] = pk;
            }
        }
        __syncthreads();

        // ---- phase 1: logitsT[16ci..+16][rows 32rg..+32], K=512 ----
        floatx4 acc1[2];
        acc1[0] = (floatx4){0.f, 0.f, 0.f, 0.f};
        acc1[1] = (floatx4){0.f, 0.f, 0.f, 0.f};
        const int r0p = 16 * (2 * rg) + l16;
        const int r1p = 16 * (2 * rg + 1) + l16;
#pragma unroll
        for (int kb = 0; kb < 4; ++kb) {
            short8 af[4];
#pragma unroll
            for (int ki = 0; ki < 4; ++ki)
                af[ki] = *(const short8*)(wb + kb * 128 + ki * 32);
#pragma unroll
            for (int ki = 0; ki < 4; ++ki) {
                const int cb = kb * 128 + ki * 32 + q * 8;
                short8 b0 = *(const short8*)&xs[r0p][cb ^ permA0];
                acc1[0] = __builtin_amdgcn_mfma_f32_16x16x32_bf16(af[ki], b0, acc1[0], 0, 0, 0);
                short8 b1 = *(const short8*)&xs[r1p][cb ^ permA1];
                acc1[1] = __builtin_amdgcn_mfma_f32_16x16x32_bf16(af[ki], b1, acc1[1], 0, 0, 0);
            }
        }

        // ---- softmax over c per row; lane: c=16ci+4q+reg, row=16(2rg+rt)+l16 ----
        float lg[2][4], rmax[2], rsi[2];
#pragma unroll
        for (int rt = 0; rt < 2; ++rt) {
#pragma unroll
            for (int reg = 0; reg < 4; ++reg) lg[rt][reg] = acc1[rt][reg] + bpv[reg];
            float m = fmaxf(fmaxf(lg[rt][0], lg[rt][1]), fmaxf(lg[rt][2], lg[rt][3]));
            m = fmaxf(m, __shfl_xor(m, 16));
            m = fmaxf(m, __shfl_xor(m, 32));
            if (lane < 16) red1[16 * (2 * rg + rt) + lane][ci] = m;
        }
        __syncthreads();
#pragma unroll
        for (int rt = 0; rt < 2; ++rt) {
            const int row = 16 * (2 * rg + rt) + l16;
            rmax[rt] = fmaxf(fmaxf(red1[row][0], red1[row][1]),
                             fmaxf(red1[row][2], red1[row][3]));
        }
#pragma unroll
        for (int rt = 0; rt < 2; ++rt) {
            float p = 0.f;
#pragma unroll
            for (int reg = 0; reg < 4; ++reg) {
                float e = __expf(lg[rt][reg] - rmax[rt]);
                lg[rt][reg] = e; p += e;
            }
            p += __shfl_xor(p, 16);
            p += __shfl_xor(p, 32);
            if (lane < 16) red2[16 * (2 * rg + rt) + lane][ci] = p;
        }
        __syncthreads();
#pragma unroll
        for (int rt = 0; rt < 2; ++rt) {
            const int row = 16 * (2 * rg + rt) + l16;
            rsi[rt] = 1.0f / (red2[row][0] + red2[row][1] +
                              red2[row][2] + red2[row][3]);
        }
#pragma unroll
        for (int rt = 0; rt < 2; ++rt) {
            const int row = 16 * (2 * rg + rt) + l16;
            bool valid = (row0 + row) < N;
#pragma unroll
            for (int reg = 0; reg < 4; ++reg) {
                float s = valid ? lg[rt][reg] * rsi[rt] : 0.f;
                sT[16 * ci + 4 * q + reg][row] = f2bf(s);
                csp[reg] += s;
            }
        }
        __syncthreads();   // sT ready; xs still intact

        // ---- phase 2: acc += s^T x over this tile (K=64 rows) ----
        short8 as_[2][4];
#pragma unroll
        for (int ks = 0; ks < 2; ++ks)
#pragma unroll
            for (int mt = 0; mt < 4; ++mt)
                as_[ks][mt] = *(const short8*)&sT[16 * mt + l16][ks * 32 + q * 8];
#pragma unroll
        for (int nt = 0; nt < 4; ++nt) {
            const int fcol = (64 * w + 16 * nt + l16) ^ (q << 4);  // swizzled col
            short8 b0, b1;
#pragma unroll
            for (int j = 0; j < 8; ++j) {
                b0[j] = (short)xs[q * 8 + j][fcol];
                b1[j] = (short)xs[32 + q * 8 + j][fcol];
            }
#pragma unroll
            for (int mt = 0; mt < 4; ++mt) {
                acc[mt][nt] = __builtin_amdgcn_mfma_f32_16x16x32_bf16(
                    as_[0][mt], b0, acc[mt][nt], 0, 0, 0);
                acc[mt][nt] = __builtin_amdgcn_mfma_f32_16x16x32_bf16(
                    as_[1][mt], b1, acc[mt][nt], 0, 0, 0);
            }
        }
    }

    // ---- per-block colsum partial (fp32, no atomics) ----
#pragma unroll
    for (int reg = 0; reg < 4; ++reg) {
        float v = csp[reg];
        v += __shfl_xor(v, 1); v += __shfl_xor(v, 2);
        v += __shfl_xor(v, 4); v += __shfl_xor(v, 8);
        if (l16 == 0) red1[16 * ci + 4 * q + reg][rg] = v;   // two waves per ci
    }
    __syncthreads();   // also: all waves done with xs (phase-2 complete)
    if (t < 64) cpart[(size_t)blockIdx.x * CDIM + t] = red1[t][0] + red1[t][1];

    // ---- flush: acc -> xs scratch (bf16) -> coalesced uint4 store ----
    ushort* xf = &xs[0][0];
#pragma unroll
    for (int mt = 0; mt < 4; ++mt)
#pragma unroll
        for (int nt = 0; nt < 4; ++nt)
#pragma unroll
            for (int reg = 0; reg < 4; ++reg)
                xf[(16 * mt + 4 * q + reg) * FDIM + 64 * w + 16 * nt + l16] =
                    f2bf(acc[mt][nt][reg]);
    __syncthreads();
    const uint4v* src = (const uint4v*)xf;
    uint4v* dst = (uint4v*)(part + (size_t)blockIdx.x * (CDIM * FDIM));
#pragma unroll
    for (int i = 0; i < 8; ++i)
        dst[i * 512 + t] = src[i * 512 + t];
}

// ---------------- stage-1 reduce: P partials -> 8 fp32 slices + colsum -----
// grid (64 c, 8 p-chunks), 512 threads (t = f).
__global__ __launch_bounds__(512) void kR(const ushort* __restrict__ part,
                                          const float* __restrict__ cpart,
                                          float* __restrict__ colsum,
                                          float* __restrict__ Mp,
                                          int P, int pch) {
    __shared__ float ws8[8];
    const int c = blockIdx.x, pc = blockIdx.y, t = threadIdx.x;
    const int p0 = pc * pch, p1 = min(p0 + pch, P);

    float sum = 0.f;
    const ushort* pp = part + (size_t)c * FDIM + t;
#pragma unroll 4
    for (int p = p0; p < p1; ++p)
        sum += bf2f((unsigned)pp[(size_t)p * (CDIM * FDIM)]);
    Mp[((size_t)pc * CDIM + c) * FDIM + t] = sum;

    // colsum chunk (p = p0 + t)
    float cv = 0.f;
    {
        int p = p0 + t;
        if (p < p1) cv = cpart[(size_t)p * CDIM + c];
    }
    cv += __shfl_xor(cv, 1);  cv += __shfl_xor(cv, 2);
    cv += __shfl_xor(cv, 4);  cv += __shfl_xor(cv, 8);
    cv += __shfl_xor(cv, 16); cv += __shfl_xor(cv, 32);
    if ((t & 63) == 0) ws8[t >> 6] = cv;
    __syncthreads();
    if (t == 0) {
        float tot = 0.f;
#pragma unroll
        for (int i = 0; i < 8; ++i) tot += ws8[i];
        atomicAdd(colsum + c, tot);     // 512 adds total, uncontended
    }
}

// ---------------- epilogue: Mp -> M -> pooled -> out -----------------------
__global__ __launch_bounds__(512) void kC(const float* __restrict__ Mp,
                                          const float* __restrict__ colsum,
                                          const float* __restrict__ We,
                                          const float* __restrict__ be,
                                          const float* __restrict__ Wo,
                                          const float* __restrict__ bo,
                                          float* __restrict__ out) {
    __shared__ float Mrow[512];
    __shared__ float pooled[512];
    __shared__ float halves[2][256];
    const int c = blockIdx.x, t = threadIdx.x;

    float sum = 0.f;
#pragma unroll
    for (int pc = 0; pc < 8; ++pc)
        sum += Mp[((size_t)pc * CDIM + c) * FDIM + t];
    Mrow[t] = sum;
    __syncthreads();

    float a = colsum[c] * be[t];
#pragma unroll 16
    for (int k = 0; k < FDIM; ++k)
        a = fmaf(Mrow[k], We[(size_t)k * FDIM + t], a);
    pooled[t] = a;
    __syncthreads();

    const int o = t & 255, h = t >> 8;
    float b = 0.f;
#pragma unroll 16
    for (int kk = 0; kk < 256; ++kk) {
        int k = h * 256 + kk;
        b = fmaf(pooled[k], Wo[(size_t)k * ODIM + o], b);
    }
    halves[h][o] = b;
    __syncthreads();
    if (t < 256)
        out[(size_t)c * ODIM + t] = halves[0][t] + halves[1][t] + bo[t];
}

// ---------------------------------------------------------------------------
extern "C" void kernel_launch(void* const* d_in, const int* in_sizes, int n_in,
                              void* d_out, int out_size, void* d_ws, size_t ws_size,
                              hipStream_t stream) {
    const float* x  = (const float*)d_in[0];
    // d_in[1] edge_index, d_in[2] batch: unused by reference output
    const float* Wp = (const float*)d_in[3];
    const float* bp = (const float*)d_in[4];
    const float* We = (const float*)d_in[5];
    const float* be = (const float*)d_in[6];
    const float* Wo = (const float*)d_in[7];
    const float* bo = (const float*)d_in[8];
    float* out = (float*)d_out;

    const int N = in_sizes[0] / FDIM;         // 50000
    const int nTiles = (N + 63) / 64;         // 782

    // ws bytes:
    //   [0,       65536)  WpT bf16
    //   [65536,   65792)  colsum fp32
    //   [66560,  266752)  cpart fp32 (<=782 x 64)
    //   [266752,1315328)  Mp fp32 (8 x 64 x 512)
    //   [1315328, ...)    part bf16 (P x 64 KB)
    char*   wsb    = (char*)d_ws;
    ushort* WpT    = (ushort*)wsb;
    float*  colsum = (float*)(wsb + 65536);
    float*  cpart  = (float*)(wsb + 66560);
    float*  Mp     = (float*)(wsb + 266752);
    const size_t PART_OFF = 1315328;
    ushort* part   = (ushort*)(wsb + PART_OFF);

    size_t avail = (ws_size > PART_OFF + 65536) ? (ws_size - PART_OFF) / 65536 : 1;
    int P = (int)(avail < (size_t)nTiles ? avail : (size_t)nTiles);
    if (P < 1) P = 1;
    const int pch = (P + 7) / 8;

    hipMemsetAsync(colsum, 0, 256, stream);
    kWpT<<<128, 256, 0, stream>>>(Wp, WpT);
    kFused<<<P, 512, 0, stream>>>(x, WpT, bp, part, cpart, N, nTiles, P);
    kR<<<dim3(CDIM, 8), 512, 0, stream>>>(part, cpart, colsum, Mp, P, pch);
    kC<<<CDIM, 512, 0, stream>>>(Mp, colsum, We, be, Wo, bo, out);
}